// Round 17
// baseline (596.568 us; speedup 1.0000x reference)
//
#include <hip/hip_runtime.h>
#include <hip/hip_bf16.h>
#include <cstddef>

#define kN 50000
#define kNP 50048   // padded to 64*782
#define kE 500000
#define kG 64
#define kDIN 64
#define kD 128
#define kH 256   // 2*D
#define kA4 512  // 4*D
#define kOUT 10
#define PCHUNK 200
#define SBLK 196    // scan blocks: 196*256 = 50176 >= kN

typedef __attribute__((ext_vector_type(8))) short bfrag_t;
typedef __attribute__((ext_vector_type(4))) float f32x4;
typedef __attribute__((ext_vector_type(2))) float f32x2;
union FragCast { uint4 u; bfrag_t f; };

// ---- static device scratch (rewritten per call) ----
__device__ __attribute__((aligned(16))) __hip_bfloat16 g_h [(size_t)kNP * kD];
__device__ __attribute__((aligned(16))) __hip_bfloat16 g_hc[(size_t)kNP * kD];
__device__ __attribute__((aligned(16))) __hip_bfloat16 g_z [(size_t)kNP * kD];  // agg scratch
__device__ __attribute__((aligned(16))) unsigned char  g_h8 [(size_t)kNP * kD]; // fp8 mirror of g_h
__device__ __attribute__((aligned(16))) unsigned char  g_hc8[(size_t)kNP * kD]; // fp8 mirror of g_hc
__device__ __attribute__((aligned(16))) __hip_bfloat16 g_A [(size_t)kNP * kA4];
__device__ __attribute__((aligned(16))) unsigned char  g_Bf8[(size_t)kNP * kA4];  // fp8 e4m3
__device__ __attribute__((aligned(16))) __hip_bfloat16 g_pk[1056 * 512];  // packed MFMA B-frags
__device__ float g_atts[kE];   // edge weights, CSR order
__device__ int   g_rowptr[kN + 1];
__device__ int   g_cnt[kN];
__device__ int   g_tmp[SBLK * 256];  // scan: exclusive-in-block prefixes
__device__ int   g_bsum[256];        // scan: per-block totals
__device__ int   g_cols[kE];
__device__ float g_pool[kG * kD];
__device__ float g_gcnt[kG];

__device__ inline float bflo(unsigned u) { union { unsigned i; float f; } c; c.i = u << 16; return c.f; }
__device__ inline float bfhi(unsigned u) { union { unsigned i; float f; } c; c.i = u & 0xffff0000u; return c.f; }
__device__ inline __hip_bfloat16* bsel(int s) { return s == 0 ? g_h : (s == 1 ? g_hc : g_z); }

// bf16x8 (uint4) -> fp8x8 (uint2) via HW packed converts
__device__ inline uint2 bf8pack(uint4 v) {
    float f[8];
    f[0] = bflo(v.x); f[1] = bfhi(v.x); f[2] = bflo(v.y); f[3] = bfhi(v.y);
    f[4] = bflo(v.z); f[5] = bfhi(v.z); f[6] = bflo(v.w); f[7] = bfhi(v.w);
    int w0 = __builtin_amdgcn_cvt_pk_fp8_f32(f[0], f[1], 0, false);
    w0 = __builtin_amdgcn_cvt_pk_fp8_f32(f[2], f[3], w0, true);
    int w1 = __builtin_amdgcn_cvt_pk_fp8_f32(f[4], f[5], 0, false);
    w1 = __builtin_amdgcn_cvt_pk_fp8_f32(f[6], f[7], w1, true);
    uint2 o; o.x = (unsigned)w0; o.y = (unsigned)w1;
    return o;
}

// ---- weight prepack: fp32 -> bf16 MFMA B-fragment order ----
struct SrcPtrs { const float* p[16]; };

__global__ __launch_bounds__(64) void prepack_kernel(SrcPtrs sp) {
    const int fs[17] = {0,64,128,192,256,320,384,448,512,576,640,704,768,896,1024,1040,1056};
    const int Ns[16] = {256,256,256,128,128,128,256,256,256,128,128,128,512,512,128,128};
    int f = blockIdx.x;
    int m = 0;
    while (f >= fs[m + 1]) m++;
    const int fl = f - fs[m];
    const int N = Ns[m];
    const int n0 = fl % (N >> 4);
    const int k0 = fl / (N >> 4);
    const int lane = threadIdx.x;
    const int q = lane >> 4, c = lane & 15;
    const float* src = sp.p[m];
    __hip_bfloat16* dst = g_pk + (size_t)f * 512 + lane * 8;
    const int kb = k0 * 32 + q * 8;
    const int n = n0 * 16 + c;
#pragma unroll
    for (int j = 0; j < 8; j++)
        dst[j] = __float2bfloat16(src[(size_t)(kb + j) * N + n]);
}

// packed offsets (bf16 elements)
#define PK_ENC_W1(l) ((size_t)(0   + (l) * 64) * 512)
#define PK_ENC_W2(l) ((size_t)(192 + (l) * 64) * 512)
#define PK_CLF_W1(l) ((size_t)(384 + (l) * 64) * 512)
#define PK_CLF_W2(l) ((size_t)(576 + (l) * 64) * 512)
#define PK_ATT_TOP   ((size_t)768 * 512)
#define PK_ATT_BOT   ((size_t)896 * 512)
#define PK_ENC_IN    ((size_t)1024 * 512)
#define PK_CLF_IN    ((size_t)1040 * 512)

__global__ __launch_bounds__(256) void zero_prep_kernel() {
    const int i = blockIdx.x * 256 + threadIdx.x;
    if (i < kN) g_cnt[i] = 0;
    if (i < kG * kD) g_pool[i] = 0.f;
    if (i < kG) g_gcnt[i] = 0.f;
}

__global__ __launch_bounds__(256) void hist_kernel(const int* __restrict__ row) {
    const int e = blockIdx.x * 256 + threadIdx.x;
    if (e < kE) atomicAdd(&g_cnt[row[e]], 1);
}

// ---- hierarchical scan ----
__global__ __launch_bounds__(256) void scan1_kernel() {
    __shared__ int sh[256];
    const int t = threadIdx.x;
    const int i = blockIdx.x * 256 + t;
    const int c = (i < kN) ? g_cnt[i] : 0;
    sh[t] = c;
    __syncthreads();
    int v = c;
    for (int off = 1; off < 256; off <<= 1) {
        int add = (t >= off) ? sh[t - off] : 0;
        __syncthreads();
        v += add;
        sh[t] = v;
        __syncthreads();
    }
    g_tmp[i] = v - c;
    if (t == 255) g_bsum[blockIdx.x] = v;
}

__global__ __launch_bounds__(256) void scan2_kernel() {
    __shared__ int sh[256];
    const int t = threadIdx.x;
    const int c = (t < SBLK) ? g_bsum[t] : 0;
    sh[t] = c;
    __syncthreads();
    int v = c;
    for (int off = 1; off < 256; off <<= 1) {
        int add = (t >= off) ? sh[t - off] : 0;
        __syncthreads();
        v += add;
        sh[t] = v;
        __syncthreads();
    }
    if (t < SBLK) g_bsum[t] = v - c;
}

__global__ __launch_bounds__(256) void scan3_kernel() {
    const int i = blockIdx.x * 256 + threadIdx.x;
    const int v = g_tmp[i] + g_bsum[blockIdx.x];
    if (i <= kN) g_rowptr[i] = v;
    if (i < kN) g_cnt[i] = v;
}

__global__ __launch_bounds__(256) void scatter_kernel(
    const int* __restrict__ row, const int* __restrict__ col) {
    const int e = blockIdx.x * 256 + threadIdx.x;
    if (e >= kE) return;
    const int r = row[e];
    const int pos = atomicAdd(&g_cnt[r], 1);
    g_cols[pos] = col[e];
}

// h = relu(x@enc_in_W+eb) -> g_h (+fp8 mirror); hc likewise -> g_hc. MFMA, K=64.
__global__ __launch_bounds__(256) void input_proj_mfma(
    const float* __restrict__ x,
    const float* __restrict__ eb, const float* __restrict__ cb) {
    __shared__ __hip_bfloat16 xs[64][72];
    __shared__ __hip_bfloat16 ob[64][264];
    const int t = threadIdx.x, lane = t & 63, w = t >> 6;
    const int node0 = blockIdx.x * 64;
#pragma unroll
    for (int it = 0; it < 4; it++) {
        int idx = t + it * 256;
        int r = idx >> 4, c = idx & 15;
        float4 v = make_float4(0.f, 0.f, 0.f, 0.f);
        if (node0 + r < kN) v = ((const float4*)x)[(size_t)(node0 + r) * 16 + c];
        union { uint2 u; __hip_bfloat16 h[4]; } o;
        o.h[0] = __float2bfloat16(v.x); o.h[1] = __float2bfloat16(v.y);
        o.h[2] = __float2bfloat16(v.z); o.h[3] = __float2bfloat16(v.w);
        *(uint2*)(&xs[r][c * 4]) = o.u;
    }
    __syncthreads();
    const int q = lane >> 4, cidx = lane & 15;
    f32x4 acc[4][4] = {};
    const uint4* pk = (const uint4*)(g_pk + (w >= 2 ? PK_CLF_IN : PK_ENC_IN));
#pragma unroll
    for (int k0 = 0; k0 < 2; k0++) {
        FragCast a[4], b[4];
#pragma unroll
        for (int mt = 0; mt < 4; mt++)
            a[mt].u = *(const uint4*)(&xs[mt * 16 + cidx][k0 * 32 + q * 8]);
#pragma unroll
        for (int nt = 0; nt < 4; nt++)
            b[nt].u = pk[(size_t)(k0 * 8 + (w & 1) * 4 + nt) * 64 + lane];
#pragma unroll
        for (int mt = 0; mt < 4; mt++)
#pragma unroll
            for (int nt = 0; nt < 4; nt++)
                acc[mt][nt] = __builtin_amdgcn_mfma_f32_16x16x32_bf16(
                    a[mt].f, b[nt].f, acc[mt][nt], 0, 0, 0);
    }
    const float* bp = (w >= 2) ? cb : eb;
#pragma unroll
    for (int nt = 0; nt < 4; nt++) {
        const int mcol = (w & 1) * 64 + nt * 16 + cidx;
        const float bv = bp[mcol];
#pragma unroll
        for (int mt = 0; mt < 4; mt++)
#pragma unroll
            for (int r = 0; r < 4; r++)
                ob[mt * 16 + q * 4 + r][w * 64 + nt * 16 + cidx] =
                    __float2bfloat16(fmaxf(acc[mt][nt][r] + bv, 0.f));
    }
    __syncthreads();
#pragma unroll
    for (int it = 0; it < 8; it++) {
        int idx = t + it * 256;
        int r = idx >> 5, c = idx & 31;
        uint4 v = *(const uint4*)(&ob[r][c * 8]);
        uint2 v8 = bf8pack(v);
        if (c < 16) {
            ((uint4*)(g_h  + (size_t)(node0 + r) * kD))[c] = v;
            ((uint2*)(g_h8 + (size_t)(node0 + r) * kD))[c] = v8;
        } else {
            ((uint4*)(g_hc  + (size_t)(node0 + r) * kD))[c - 16] = v;
            ((uint2*)(g_hc8 + (size_t)(node0 + r) * kD))[c - 16] = v8;
        }
    }
}

// fp8x8 (uint2) accumulate into 4 f32x2 regs
__device__ inline void f8acc(uint2 v, f32x2 wt, f32x2& c0, f32x2& c1, f32x2& c2, f32x2& c3) {
    c0 = c0 + __builtin_amdgcn_cvt_pk_f32_fp8(v.x, false) * wt;
    c1 = c1 + __builtin_amdgcn_cvt_pk_f32_fp8(v.x, true)  * wt;
    c2 = c2 + __builtin_amdgcn_cvt_pk_f32_fp8(v.y, false) * wt;
    c3 = c3 + __builtin_amdgcn_cvt_pk_f32_fp8(v.y, true)  * wt;
}
__device__ inline void f8sum(uint2 v, f32x2& c0, f32x2& c1, f32x2& c2, f32x2& c3) {
    c0 = c0 + __builtin_amdgcn_cvt_pk_f32_fp8(v.x, false);
    c1 = c1 + __builtin_amdgcn_cvt_pk_f32_fp8(v.x, true);
    c2 = c2 + __builtin_amdgcn_cvt_pk_f32_fp8(v.y, false);
    c3 = c3 + __builtin_amdgcn_cvt_pk_f32_fp8(v.y, true);
}
// fp8x16 (uint4) accumulate into 8 f32x2 regs
__device__ inline void f8acc4(uint4 v, f32x2 wt, f32x2* c) {
    c[0] = c[0] + __builtin_amdgcn_cvt_pk_f32_fp8(v.x, false) * wt;
    c[1] = c[1] + __builtin_amdgcn_cvt_pk_f32_fp8(v.x, true)  * wt;
    c[2] = c[2] + __builtin_amdgcn_cvt_pk_f32_fp8(v.y, false) * wt;
    c[3] = c[3] + __builtin_amdgcn_cvt_pk_f32_fp8(v.y, true)  * wt;
    c[4] = c[4] + __builtin_amdgcn_cvt_pk_f32_fp8(v.z, false) * wt;
    c[5] = c[5] + __builtin_amdgcn_cvt_pk_f32_fp8(v.z, true)  * wt;
    c[6] = c[6] + __builtin_amdgcn_cvt_pk_f32_fp8(v.w, false) * wt;
    c[7] = c[7] + __builtin_amdgcn_cvt_pk_f32_fp8(v.w, true)  * wt;
}

// CSR aggregation (R15 form): z[n] = h[n](bf16) + sum_j h8[col[j]](fp8)*att?.
// 16 lanes/node (uint2 = 8 dims each), x4 unroll. No LDS -> full occupancy.
__global__ __launch_bounds__(256) void agg_csr_kernel(int src_sel, int use_att) {
    const int t = threadIdx.x;
    const int node = blockIdx.x * 16 + (t >> 4);
    const int li = t & 15;
    const uint4* __restrict__ src  = (const uint4*)bsel(src_sel);
    const uint2* __restrict__ src8 = (const uint2*)(src_sel == 0 ? g_h8 : g_hc8);
    f32x2 c0 = {0.f, 0.f}, c1 = {0.f, 0.f}, c2 = {0.f, 0.f}, c3 = {0.f, 0.f};
    if (node < kN) {
        const uint4 sv = src[(size_t)node * 16 + li];  // self term stays bf16
        c0 = (f32x2){bflo(sv.x), bfhi(sv.x)};
        c1 = (f32x2){bflo(sv.y), bfhi(sv.y)};
        c2 = (f32x2){bflo(sv.z), bfhi(sv.z)};
        c3 = (f32x2){bflo(sv.w), bfhi(sv.w)};
        const int beg = g_rowptr[node], end = g_rowptr[node + 1];
        int j = beg;
        if (use_att) {
            for (; j + 4 <= end; j += 4) {
                const uint2 v0 = src8[(size_t)g_cols[j    ] * 16 + li];
                const uint2 v1 = src8[(size_t)g_cols[j + 1] * 16 + li];
                const uint2 v2 = src8[(size_t)g_cols[j + 2] * 16 + li];
                const uint2 v3 = src8[(size_t)g_cols[j + 3] * 16 + li];
                const float w0 = g_atts[j],     w1 = g_atts[j + 1];
                const float w2 = g_atts[j + 2], w3 = g_atts[j + 3];
                f8acc(v0, (f32x2){w0, w0}, c0, c1, c2, c3);
                f8acc(v1, (f32x2){w1, w1}, c0, c1, c2, c3);
                f8acc(v2, (f32x2){w2, w2}, c0, c1, c2, c3);
                f8acc(v3, (f32x2){w3, w3}, c0, c1, c2, c3);
            }
            for (; j < end; j++) {
                const uint2 v = src8[(size_t)g_cols[j] * 16 + li];
                const float wt = g_atts[j];
                f8acc(v, (f32x2){wt, wt}, c0, c1, c2, c3);
            }
        } else {
            for (; j + 4 <= end; j += 4) {
                const uint2 v0 = src8[(size_t)g_cols[j    ] * 16 + li];
                const uint2 v1 = src8[(size_t)g_cols[j + 1] * 16 + li];
                const uint2 v2 = src8[(size_t)g_cols[j + 2] * 16 + li];
                const uint2 v3 = src8[(size_t)g_cols[j + 3] * 16 + li];
                f8sum(v0, c0, c1, c2, c3);
                f8sum(v1, c0, c1, c2, c3);
                f8sum(v2, c0, c1, c2, c3);
                f8sum(v3, c0, c1, c2, c3);
            }
            for (; j < end; j++) {
                const uint2 v = src8[(size_t)g_cols[j] * 16 + li];
                f8sum(v, c0, c1, c2, c3);
            }
        }
    }
    union { uint4 u; __hip_bfloat16 h[8]; } o;
    o.h[0] = __float2bfloat16(c0.x); o.h[1] = __float2bfloat16(c0.y);
    o.h[2] = __float2bfloat16(c1.x); o.h[3] = __float2bfloat16(c1.y);
    o.h[4] = __float2bfloat16(c2.x); o.h[5] = __float2bfloat16(c2.y);
    o.h[6] = __float2bfloat16(c3.x); o.h[7] = __float2bfloat16(c3.y);
    ((uint4*)g_z)[(size_t)node * 16 + li] = o.u;
}

// MFMA GIN MLP: h_dst = [relu]( relu(z @ W1 + b1) @ W2 + b2 ) + fp8 mirror.
__global__ __launch_bounds__(256) void gin_mlp_mfma(
    int dst_sel, size_t pkW1off, size_t pkW2off,
    const float* __restrict__ b1, const float* __restrict__ b2, int relu_out) {
    __shared__ __hip_bfloat16 zs[64][136];
    __shared__ __hip_bfloat16 hid[64][264];
    const int t = threadIdx.x, lane = t & 63, w = t >> 6;
    const int node0 = blockIdx.x * 64;
    __hip_bfloat16* hp = bsel(dst_sel);
    unsigned char* mp = dst_sel == 0 ? g_h8 : g_hc8;

    {
        const uint4* src = (const uint4*)(g_z + (size_t)node0 * kD);
#pragma unroll
        for (int it = 0; it < 4; it++) {
            int idx = t + it * 256;
            int r = idx >> 4, c = idx & 15;
            *(uint4*)(&zs[r][c * 8]) = src[(size_t)r * 16 + c];
        }
    }
    __syncthreads();

    const int q = lane >> 4, cidx = lane & 15;

    f32x4 acc1[4][4] = {};
    const uint4* pk1 = (const uint4*)(g_pk + pkW1off);
    for (int k0 = 0; k0 < 4; k0++) {
        FragCast a[4], b[4];
#pragma unroll
        for (int mt = 0; mt < 4; mt++)
            a[mt].u = *(const uint4*)(&zs[mt * 16 + cidx][k0 * 32 + q * 8]);
#pragma unroll
        for (int nt = 0; nt < 4; nt++)
            b[nt].u = pk1[(size_t)(k0 * 16 + (w * 4 + nt)) * 64 + lane];
#pragma unroll
        for (int mt = 0; mt < 4; mt++)
#pragma unroll
            for (int nt = 0; nt < 4; nt++)
                acc1[mt][nt] = __builtin_amdgcn_mfma_f32_16x16x32_bf16(
                    a[mt].f, b[nt].f, acc1[mt][nt], 0, 0, 0);
    }
#pragma unroll
    for (int nt = 0; nt < 4; nt++) {
        const int col = w * 64 + nt * 16 + cidx;
        const float bv = b1[col];
#pragma unroll
        for (int mt = 0; mt < 4; mt++)
#pragma unroll
            for (int r = 0; r < 4; r++)
                hid[mt * 16 + q * 4 + r][col] =
                    __float2bfloat16(fmaxf(acc1[mt][nt][r] + bv, 0.f));
    }
    __syncthreads();

    f32x4 acc2[4][2] = {};
    const uint4* pk2 = (const uint4*)(g_pk + pkW2off);
    for (int k0 = 0; k0 < 8; k0++) {
        FragCast a[4], b[2];
#pragma unroll
        for (int mt = 0; mt < 4; mt++)
            a[mt].u = *(const uint4*)(&hid[mt * 16 + cidx][k0 * 32 + q * 8]);
#pragma unroll
        for (int nt = 0; nt < 2; nt++)
            b[nt].u = pk2[(size_t)(k0 * 8 + (w * 2 + nt)) * 64 + lane];
#pragma unroll
        for (int mt = 0; mt < 4; mt++)
#pragma unroll
            for (int nt = 0; nt < 2; nt++)
                acc2[mt][nt] = __builtin_amdgcn_mfma_f32_16x16x32_bf16(
                    a[mt].f, b[nt].f, acc2[mt][nt], 0, 0, 0);
    }
#pragma unroll
    for (int nt = 0; nt < 2; nt++) {
        const int col = w * 32 + nt * 16 + cidx;
        const float bv = b2[col];
#pragma unroll
        for (int mt = 0; mt < 4; mt++)
#pragma unroll
            for (int r = 0; r < 4; r++) {
                float v = acc2[mt][nt][r] + bv;
                if (relu_out) v = fmaxf(v, 0.f);
                zs[mt * 16 + q * 4 + r][col] = __float2bfloat16(v);
            }
    }
    __syncthreads();
    {
        uint4* dst = (uint4*)(hp + (size_t)node0 * kD);
        uint2* md  = (uint2*)(mp + (size_t)node0 * kD);
#pragma unroll
        for (int it = 0; it < 4; it++) {
            int idx = t + it * 256;
            int r = idx >> 4, c = idx & 15;
            uint4 v = *(const uint4*)(&zs[r][c * 8]);
            dst[(size_t)r * 16 + c] = v;
            md[(size_t)r * 16 + c] = bf8pack(v);
        }
    }
}

// A (bf16) / B (fp8 e4m3, HW packed cvt) = enc_h @ attW1_{top,bot} (+b1 for A).
__global__ __launch_bounds__(256) void att_dense_mfma(const float* __restrict__ b1) {
    __shared__ __hip_bfloat16 zs[64][136];
    __shared__ __hip_bfloat16 ob[64][264];
    const int t = threadIdx.x, lane = t & 63, w = t >> 6;
    const int node0 = blockIdx.x * 64;
    const int mat = blockIdx.y >> 1, half = blockIdx.y & 1;
    const size_t pkoff = mat ? PK_ATT_BOT : PK_ATT_TOP;

    const uint4* src = (const uint4*)(g_h + (size_t)node0 * kD);
#pragma unroll
    for (int it = 0; it < 4; it++) {
        int idx = t + it * 256;
        int r = idx >> 4, c = idx & 15;
        *(uint4*)(&zs[r][c * 8]) = src[(size_t)r * 16 + c];
    }
    __syncthreads();

    const int q = lane >> 4, cidx = lane & 15;
    f32x4 acc[4][4] = {};
    const uint4* pk = (const uint4*)(g_pk + pkoff);
    for (int k0 = 0; k0 < 4; k0++) {
        FragCast a[4], b[4];
#pragma unroll
        for (int mt = 0; mt < 4; mt++)
            a[mt].u = *(const uint4*)(&zs[mt * 16 + cidx][k0 * 32 + q * 8]);
#pragma unroll
        for (int nt = 0; nt < 4; nt++)
            b[nt].u = pk[(size_t)(k0 * 32 + (half * 16 + w * 4 + nt)) * 64 + lane];
#pragma unroll
        for (int mt = 0; mt < 4; mt++)
#pragma unroll
            for (int nt = 0; nt < 4; nt++)
                acc[mt][nt] = __builtin_amdgcn_mfma_f32_16x16x32_bf16(
                    a[mt].f, b[nt].f, acc[mt][nt], 0, 0, 0);
    }
#pragma unroll
    for (int nt = 0; nt < 4; nt++) {
        const int lcol = w * 64 + nt * 16 + cidx;
        const float bv = (mat == 0) ? b1[half * 256 + lcol] : 0.f;
#pragma unroll
        for (int mt = 0; mt < 4; mt++)
#pragma unroll
            for (int r = 0; r < 4; r++)
                ob[mt * 16 + q * 4 + r][lcol] = __float2bfloat16(acc[mt][nt][r] + bv);
    }
    __syncthreads();
    if (mat == 0) {   // A: bf16
        uint4* dst = (uint4*)(g_A + (size_t)node0 * kA4 + half * 256);
#pragma unroll
        for (int it = 0; it < 8; it++) {
            int idx = t + it * 256;
            int r = idx >> 5, c = idx & 31;
            dst[(size_t)r * 64 + c] = *(const uint4*)(&ob[r][c * 8]);
        }
    } else {          // B: fp8 e4m3
        uint2* dst = (uint2*)(g_Bf8 + (size_t)node0 * kA4 + half * 256);
#pragma unroll
        for (int it = 0; it < 8; it++) {
            int idx = t + it * 256;
            int r = idx >> 5, c = idx & 31;
            dst[(size_t)r * 64 + c] = bf8pack(*(const uint4*)(&ob[r][c * 8]));
        }
    }
}

// Packed-f32 fp8 dot: 16 dims as 8 f32x2 lanes; HW v_cvt_pk_f32_fp8 decode.
__device__ inline float edge_dot16_f8(const f32x2* a2, const f32x2* w2, uint4 bu) {
    const f32x2 zero = {0.f, 0.f};
    f32x2 p = zero;
    const unsigned wd[4] = {bu.x, bu.y, bu.z, bu.w};
#pragma unroll
    for (int k = 0; k < 4; k++) {
        f32x2 b0 = __builtin_amdgcn_cvt_pk_f32_fp8(wd[k], false);
        f32x2 b1 = __builtin_amdgcn_cvt_pk_f32_fp8(wd[k], true);
        f32x2 t0 = __builtin_elementwise_max(a2[2 * k] + b0, zero);
        f32x2 t1 = __builtin_elementwise_max(a2[2 * k + 1] + b1, zero);
        p = p + t0 * w2[2 * k];
        p = p + t1 * w2[2 * k + 1];
    }
    return p.x + p.y;
}

// FUSED att + first classifier agg: per node, per edge compute att (B-gather +
// dot + reduce) then immediately accumulate hc8[col]*att into the node message.
// Shares the CSR walk and col indices between the two former kernels.
// Writes g_atts (for clf layers 2,3) and g_z (for clf mlp layer 1).
__global__ __launch_bounds__(256) void att_agg_fused(
    const float* __restrict__ W2, const float* __restrict__ b2) {
    const int node = blockIdx.x * 4 + (threadIdx.x >> 6);  // wave per node
    const int lane = threadIdx.x & 63;
    const int sub = lane >> 5;   // edge sub-group 0/1
    const int li  = lane & 31;
    const int m0 = li * 16;
    const uint4 au0 = *(const uint4*)(g_A + (size_t)node * kA4 + m0);
    const uint4 au1 = *(const uint4*)(g_A + (size_t)node * kA4 + m0 + 8);
    f32x2 a2[8];
    a2[0] = (f32x2){bflo(au0.x), bfhi(au0.x)};
    a2[1] = (f32x2){bflo(au0.y), bfhi(au0.y)};
    a2[2] = (f32x2){bflo(au0.z), bfhi(au0.z)};
    a2[3] = (f32x2){bflo(au0.w), bfhi(au0.w)};
    a2[4] = (f32x2){bflo(au1.x), bfhi(au1.x)};
    a2[5] = (f32x2){bflo(au1.y), bfhi(au1.y)};
    a2[6] = (f32x2){bflo(au1.z), bfhi(au1.z)};
    a2[7] = (f32x2){bflo(au1.w), bfhi(au1.w)};
    f32x2 w2r[8];
#pragma unroll
    for (int k = 0; k < 8; k++) {
        const float2 wk = *(const float2*)(W2 + m0 + 2 * k);
        w2r[k] = (f32x2){wk.x, wk.y};
    }
    const float bb = b2[0];

    // node accumulator: lanes li<8 hold dims [li*16, li*16+16); sub0 seeds self
    f32x2 acc[8] = {};
    if (sub == 0 && li < 8) {
        const uint4 s0 = ((const uint4*)g_hc)[(size_t)node * 16 + 2 * li];
        const uint4 s1 = ((const uint4*)g_hc)[(size_t)node * 16 + 2 * li + 1];
        acc[0] = (f32x2){bflo(s0.x), bfhi(s0.x)};
        acc[1] = (f32x2){bflo(s0.y), bfhi(s0.y)};
        acc[2] = (f32x2){bflo(s0.z), bfhi(s0.z)};
        acc[3] = (f32x2){bflo(s0.w), bfhi(s0.w)};
        acc[4] = (f32x2){bflo(s1.x), bfhi(s1.x)};
        acc[5] = (f32x2){bflo(s1.y), bfhi(s1.y)};
        acc[6] = (f32x2){bflo(s1.z), bfhi(s1.z)};
        acc[7] = (f32x2){bflo(s1.w), bfhi(s1.w)};
    }
    const int beg = g_rowptr[node], end = g_rowptr[node + 1];

    int j = beg;
    for (; j + 4 <= end; j += 4) {
        const int c0 = g_cols[j + sub];
        const int c1 = g_cols[j + 2 + sub];
        const uint4 b0 = *(const uint4*)(g_Bf8 + (size_t)c0 * kA4 + m0);
        const uint4 b1 = *(const uint4*)(g_Bf8 + (size_t)c1 * kA4 + m0);
        float s0 = edge_dot16_f8(a2, w2r, b0);
        float s1 = edge_dot16_f8(a2, w2r, b1);
        for (int off = 16; off > 0; off >>= 1) {
            s0 += __shfl_down(s0, off);
            s1 += __shfl_down(s1, off);
        }
        const float att0 = 1.f / (1.f + __expf(-(__shfl(s0, sub * 32) + bb)));
        const float att1 = 1.f / (1.f + __expf(-(__shfl(s1, sub * 32) + bb)));
        if (li == 0) {
            g_atts[j + sub]     = att0;
            g_atts[j + 2 + sub] = att1;
        }
        if (li < 8) {
            const uint4 m0v = ((const uint4*)g_hc8)[(size_t)c0 * 8 + li];
            const uint4 m1v = ((const uint4*)g_hc8)[(size_t)c1 * 8 + li];
            f8acc4(m0v, (f32x2){att0, att0}, acc);
            f8acc4(m1v, (f32x2){att1, att1}, acc);
        }
    }
    for (; j < end; j += 2) {
        const int je = j + sub;
        const bool ok = je < end;
        const int c = g_cols[ok ? je : end - 1];
        const uint4 b0 = *(const uint4*)(g_Bf8 + (size_t)c * kA4 + m0);
        float s = edge_dot16_f8(a2, w2r, b0);
        for (int off = 16; off > 0; off >>= 1) s += __shfl_down(s, off);
        const float att = 1.f / (1.f + __expf(-(__shfl(s, sub * 32) + bb)));
        if (ok) {
            if (li == 0) g_atts[je] = att;
            if (li < 8) {
                const uint4 mv = ((const uint4*)g_hc8)[(size_t)c * 8 + li];
                f8acc4(mv, (f32x2){att, att}, acc);
            }
        }
    }
    // combine sub halves (partner lane = lane ^ 32)
#pragma unroll
    for (int r = 0; r < 8; r++) {
        acc[r].x += __shfl(acc[r].x, lane ^ 32);
        acc[r].y += __shfl(acc[r].y, lane ^ 32);
    }
    if (sub == 0 && li < 8) {
        union { uint4 u; __hip_bfloat16 h[8]; } o0, o1;
        o0.h[0] = __float2bfloat16(acc[0].x); o0.h[1] = __float2bfloat16(acc[0].y);
        o0.h[2] = __float2bfloat16(acc[1].x); o0.h[3] = __float2bfloat16(acc[1].y);
        o0.h[4] = __float2bfloat16(acc[2].x); o0.h[5] = __float2bfloat16(acc[2].y);
        o0.h[6] = __float2bfloat16(acc[3].x); o0.h[7] = __float2bfloat16(acc[3].y);
        o1.h[0] = __float2bfloat16(acc[4].x); o1.h[1] = __float2bfloat16(acc[4].y);
        o1.h[2] = __float2bfloat16(acc[5].x); o1.h[3] = __float2bfloat16(acc[5].y);
        o1.h[4] = __float2bfloat16(acc[6].x); o1.h[5] = __float2bfloat16(acc[6].y);
        o1.h[6] = __float2bfloat16(acc[7].x); o1.h[7] = __float2bfloat16(acc[7].y);
        ((uint4*)g_z)[(size_t)node * 16 + 2 * li]     = o0.u;
        ((uint4*)g_z)[(size_t)node * 16 + 2 * li + 1] = o1.u;
    }
}

// Segmented mean-pool over sorted batch; final classifier h lives in g_hc.
__global__ __launch_bounds__(64) void pool_kernel(const int* __restrict__ batch) {
    const int t = threadIdx.x;
    int n = blockIdx.x * PCHUNK;
    const int nend = n + PCHUNK;
    const unsigned* __restrict__ hc = (const unsigned*)g_hc;
    int gcur = batch[n];
    float a0 = 0.f, a1 = 0.f, cv = 0.f;
    for (; n < nend; n++) {
        const int g = batch[n];
        if (g != gcur) {
            atomicAdd(&g_pool[gcur * kD + 2 * t], a0);
            atomicAdd(&g_pool[gcur * kD + 2 * t + 1], a1);
            if (t == 0) atomicAdd(&g_gcnt[gcur], cv);
            a0 = a1 = cv = 0.f; gcur = g;
        }
        unsigned v = hc[(size_t)n * 64 + t];
        a0 += bflo(v); a1 += bfhi(v);
        cv += 1.f;
    }
    atomicAdd(&g_pool[gcur * kD + 2 * t], a0);
    atomicAdd(&g_pool[gcur * kD + 2 * t + 1], a1);
    if (t == 0) atomicAdd(&g_gcnt[gcur], cv);
}

__global__ __launch_bounds__(640) void head_kernel(
    const float* __restrict__ hW, const float* __restrict__ hb,
    float* __restrict__ out) {
    const int t = threadIdx.x;
    const int g = t / kOUT, o = t - g * kOUT;
    const float c = fmaxf(g_gcnt[g], 1.f);
    const float inv = 1.f / c;
    float acc = hb[o];
    for (int k = 0; k < kD; k++)
        acc = fmaf(g_pool[g * kD + k] * inv, hW[k * kOUT + o], acc);
    out[(size_t)g * kOUT + o] = acc;
}

extern "C" void kernel_launch(void* const* d_in, const int* in_sizes, int n_in,
                              void* d_out, int out_size, void* d_ws, size_t ws_size,
                              hipStream_t stream) {
    const float* x        = (const float*)d_in[0];
    const int*   ei       = (const int*)d_in[1];
    const int*   row      = ei;
    const int*   col      = ei + kE;
    const int*   batch    = (const int*)d_in[2];
    const float* enc_in_W = (const float*)d_in[4];
    const float* enc_in_b = (const float*)d_in[5];
    const float* enc_W1   = (const float*)d_in[6];
    const float* enc_b1   = (const float*)d_in[7];
    const float* enc_W2   = (const float*)d_in[8];
    const float* enc_b2   = (const float*)d_in[9];
    const float* att_W1   = (const float*)d_in[10];
    const float* att_b1   = (const float*)d_in[11];
    const float* att_W2   = (const float*)d_in[12];
    const float* att_b2   = (const float*)d_in[13];
    const float* clf_in_W = (const float*)d_in[14];
    const float* clf_in_b = (const float*)d_in[15];
    const float* clf_W1   = (const float*)d_in[16];
    const float* clf_b1   = (const float*)d_in[17];
    const float* clf_W2   = (const float*)d_in[18];
    const float* clf_b2   = (const float*)d_in[19];
    const float* head_W   = (const float*)d_in[20];
    const float* head_b   = (const float*)d_in[21];
    float* out = (float*)d_out;

    const dim3 blk(256);
    const int eblocks = (kE + 255) / 256;

    // ---- weight prepack ----
    SrcPtrs sp;
    for (int l = 0; l < 3; l++) {
        sp.p[0 + l] = enc_W1 + (size_t)l * kD * kH;
        sp.p[3 + l] = enc_W2 + (size_t)l * kH * kD;
        sp.p[6 + l] = clf_W1 + (size_t)l * kD * kH;
        sp.p[9 + l] = clf_W2 + (size_t)l * kH * kD;
    }
    sp.p[12] = att_W1;
    sp.p[13] = att_W1 + (size_t)kD * kA4;
    sp.p[14] = enc_in_W;
    sp.p[15] = clf_in_W;
    prepack_kernel<<<1056, dim3(64), 0, stream>>>(sp);

    // ---- CSR build (hierarchical scan) ----
    zero_prep_kernel<<<(kN + 255) / 256, blk, 0, stream>>>();
    hist_kernel<<<eblocks, blk, 0, stream>>>(row);
    scan1_kernel<<<SBLK, blk, 0, stream>>>();
    scan2_kernel<<<1, blk, 0, stream>>>();
    scan3_kernel<<<SBLK, blk, 0, stream>>>();
    scatter_kernel<<<eblocks, blk, 0, stream>>>(row, col);

    input_proj_mfma<<<kNP / 64, blk, 0, stream>>>(x, enc_in_b, clf_in_b);

    // ---- encoder GIN stack (agg: g_h -> g_z; mlp: g_z -> g_h) ----
    for (int l = 0; l < 3; l++) {
        agg_csr_kernel<<<kNP / 16, blk, 0, stream>>>(0, 0);
        gin_mlp_mfma<<<kNP / 64, blk, 0, stream>>>(
            0, PK_ENC_W1(l), PK_ENC_W2(l),
            enc_b1 + (size_t)l * kH, enc_b2 + (size_t)l * kD, (l < 2) ? 1 : 0);
    }

    // ---- edge attention + fused clf agg layer 0 ----
    att_dense_mfma<<<dim3(kNP / 64, 4), blk, 0, stream>>>(att_b1);
    att_agg_fused<<<kN / 4, blk, 0, stream>>>(att_W2, att_b2);
    gin_mlp_mfma<<<kNP / 64, blk, 0, stream>>>(
        1, PK_CLF_W1(0), PK_CLF_W2(0), clf_b1, clf_b2, 1);

    // ---- classifier GIN stack layers 1,2 (agg: g_hc -> g_z; mlp: g_z -> g_hc) ----
    for (int l = 1; l < 3; l++) {
        agg_csr_kernel<<<kNP / 16, blk, 0, stream>>>(1, 1);
        gin_mlp_mfma<<<kNP / 64, blk, 0, stream>>>(
            1, PK_CLF_W1(l), PK_CLF_W2(l),
            clf_b1 + (size_t)l * kH, clf_b2 + (size_t)l * kD, (l < 2) ? 1 : 0);
    }

    // ---- mean pool + head ----
    pool_kernel<<<kN / PCHUNK, dim3(64), 0, stream>>>(batch);
    head_kernel<<<1, dim3(kG * kOUT), 0, stream>>>(head_W, head_b, out);
}

// Round 18
// 569.996 us; speedup vs baseline: 1.0466x; 1.0466x over previous
//
#include <hip/hip_runtime.h>
#include <hip/hip_bf16.h>
#include <cstddef>

#define kN 50000
#define kNP 50048   // padded to 64*782
#define kE 500000
#define kG 64
#define kDIN 64
#define kD 128
#define kH 256   // 2*D
#define kA4 512  // 4*D
#define kOUT 10
#define PCHUNK 200
#define SBLK 196    // scan blocks: 196*256 = 50176 >= kN

typedef __attribute__((ext_vector_type(8))) short bfrag_t;
typedef __attribute__((ext_vector_type(4))) float f32x4;
typedef __attribute__((ext_vector_type(2))) float f32x2;
union FragCast { uint4 u; bfrag_t f; };

// ---- static device scratch (rewritten per call) ----
__device__ __attribute__((aligned(16))) __hip_bfloat16 g_h [(size_t)kNP * kD];
__device__ __attribute__((aligned(16))) __hip_bfloat16 g_hc[(size_t)kNP * kD];
__device__ __attribute__((aligned(16))) __hip_bfloat16 g_z [(size_t)kNP * kD];  // agg scratch
__device__ __attribute__((aligned(16))) unsigned char  g_h8 [(size_t)kNP * kD]; // fp8 mirror of g_h
__device__ __attribute__((aligned(16))) unsigned char  g_hc8[(size_t)kNP * kD]; // fp8 mirror of g_hc
__device__ __attribute__((aligned(16))) __hip_bfloat16 g_A [(size_t)kNP * kA4];
__device__ __attribute__((aligned(16))) unsigned char  g_Bf8[(size_t)kNP * kA4];  // fp8 e4m3
__device__ __attribute__((aligned(16))) __hip_bfloat16 g_pk[1056 * 512];  // packed MFMA B-frags
__device__ float g_atts[kE];   // edge weights, CSR order
__device__ int   g_rowptr[kN + 1];
__device__ int   g_cnt[kN];
__device__ int   g_tmp[SBLK * 256];  // scan: exclusive-in-block prefixes
__device__ int   g_bsum[256];        // scan: per-block totals
__device__ int   g_cols[kE];
__device__ float g_pool[kG * kD];
__device__ float g_gcnt[kG];

__device__ inline float bflo(unsigned u) { union { unsigned i; float f; } c; c.i = u << 16; return c.f; }
__device__ inline float bfhi(unsigned u) { union { unsigned i; float f; } c; c.i = u & 0xffff0000u; return c.f; }
__device__ inline __hip_bfloat16* bsel(int s) { return s == 0 ? g_h : (s == 1 ? g_hc : g_z); }

// bf16x8 (uint4) -> fp8x8 (uint2) via HW packed converts
__device__ inline uint2 bf8pack(uint4 v) {
    float f[8];
    f[0] = bflo(v.x); f[1] = bfhi(v.x); f[2] = bflo(v.y); f[3] = bfhi(v.y);
    f[4] = bflo(v.z); f[5] = bfhi(v.z); f[6] = bflo(v.w); f[7] = bfhi(v.w);
    int w0 = __builtin_amdgcn_cvt_pk_fp8_f32(f[0], f[1], 0, false);
    w0 = __builtin_amdgcn_cvt_pk_fp8_f32(f[2], f[3], w0, true);
    int w1 = __builtin_amdgcn_cvt_pk_fp8_f32(f[4], f[5], 0, false);
    w1 = __builtin_amdgcn_cvt_pk_fp8_f32(f[6], f[7], w1, true);
    uint2 o; o.x = (unsigned)w0; o.y = (unsigned)w1;
    return o;
}

// ---- weight prepack: fp32 -> bf16 MFMA B-fragment order ----
struct SrcPtrs { const float* p[16]; };

__global__ __launch_bounds__(64) void prepack_kernel(SrcPtrs sp) {
    const int fs[17] = {0,64,128,192,256,320,384,448,512,576,640,704,768,896,1024,1040,1056};
    const int Ns[16] = {256,256,256,128,128,128,256,256,256,128,128,128,512,512,128,128};
    int f = blockIdx.x;
    int m = 0;
    while (f >= fs[m + 1]) m++;
    const int fl = f - fs[m];
    const int N = Ns[m];
    const int n0 = fl % (N >> 4);
    const int k0 = fl / (N >> 4);
    const int lane = threadIdx.x;
    const int q = lane >> 4, c = lane & 15;
    const float* src = sp.p[m];
    __hip_bfloat16* dst = g_pk + (size_t)f * 512 + lane * 8;
    const int kb = k0 * 32 + q * 8;
    const int n = n0 * 16 + c;
#pragma unroll
    for (int j = 0; j < 8; j++)
        dst[j] = __float2bfloat16(src[(size_t)(kb + j) * N + n]);
}

// packed offsets (bf16 elements)
#define PK_ENC_W1(l) ((size_t)(0   + (l) * 64) * 512)
#define PK_ENC_W2(l) ((size_t)(192 + (l) * 64) * 512)
#define PK_CLF_W1(l) ((size_t)(384 + (l) * 64) * 512)
#define PK_CLF_W2(l) ((size_t)(576 + (l) * 64) * 512)
#define PK_ATT_TOP   ((size_t)768 * 512)
#define PK_ATT_BOT   ((size_t)896 * 512)
#define PK_ENC_IN    ((size_t)1024 * 512)
#define PK_CLF_IN    ((size_t)1040 * 512)

__global__ __launch_bounds__(256) void zero_prep_kernel() {
    const int i = blockIdx.x * 256 + threadIdx.x;
    if (i < kN) g_cnt[i] = 0;
    if (i < kG * kD) g_pool[i] = 0.f;
    if (i < kG) g_gcnt[i] = 0.f;
}

__global__ __launch_bounds__(256) void hist_kernel(const int* __restrict__ row) {
    const int e = blockIdx.x * 256 + threadIdx.x;
    if (e < kE) atomicAdd(&g_cnt[row[e]], 1);
}

// ---- hierarchical scan ----
__global__ __launch_bounds__(256) void scan1_kernel() {
    __shared__ int sh[256];
    const int t = threadIdx.x;
    const int i = blockIdx.x * 256 + t;
    const int c = (i < kN) ? g_cnt[i] : 0;
    sh[t] = c;
    __syncthreads();
    int v = c;
    for (int off = 1; off < 256; off <<= 1) {
        int add = (t >= off) ? sh[t - off] : 0;
        __syncthreads();
        v += add;
        sh[t] = v;
        __syncthreads();
    }
    g_tmp[i] = v - c;
    if (t == 255) g_bsum[blockIdx.x] = v;
}

__global__ __launch_bounds__(256) void scan2_kernel() {
    __shared__ int sh[256];
    const int t = threadIdx.x;
    const int c = (t < SBLK) ? g_bsum[t] : 0;
    sh[t] = c;
    __syncthreads();
    int v = c;
    for (int off = 1; off < 256; off <<= 1) {
        int add = (t >= off) ? sh[t - off] : 0;
        __syncthreads();
        v += add;
        sh[t] = v;
        __syncthreads();
    }
    if (t < SBLK) g_bsum[t] = v - c;
}

__global__ __launch_bounds__(256) void scan3_kernel() {
    const int i = blockIdx.x * 256 + threadIdx.x;
    const int v = g_tmp[i] + g_bsum[blockIdx.x];
    if (i <= kN) g_rowptr[i] = v;
    if (i < kN) g_cnt[i] = v;
}

__global__ __launch_bounds__(256) void scatter_kernel(
    const int* __restrict__ row, const int* __restrict__ col) {
    const int e = blockIdx.x * 256 + threadIdx.x;
    if (e >= kE) return;
    const int r = row[e];
    const int pos = atomicAdd(&g_cnt[r], 1);
    g_cols[pos] = col[e];
}

// h = relu(x@enc_in_W+eb) -> g_h (+fp8 mirror); hc likewise -> g_hc. MFMA, K=64.
__global__ __launch_bounds__(256) void input_proj_mfma(
    const float* __restrict__ x,
    const float* __restrict__ eb, const float* __restrict__ cb) {
    __shared__ __hip_bfloat16 xs[64][72];
    __shared__ __hip_bfloat16 ob[64][264];
    const int t = threadIdx.x, lane = t & 63, w = t >> 6;
    const int node0 = blockIdx.x * 64;
#pragma unroll
    for (int it = 0; it < 4; it++) {
        int idx = t + it * 256;
        int r = idx >> 4, c = idx & 15;
        float4 v = make_float4(0.f, 0.f, 0.f, 0.f);
        if (node0 + r < kN) v = ((const float4*)x)[(size_t)(node0 + r) * 16 + c];
        union { uint2 u; __hip_bfloat16 h[4]; } o;
        o.h[0] = __float2bfloat16(v.x); o.h[1] = __float2bfloat16(v.y);
        o.h[2] = __float2bfloat16(v.z); o.h[3] = __float2bfloat16(v.w);
        *(uint2*)(&xs[r][c * 4]) = o.u;
    }
    __syncthreads();
    const int q = lane >> 4, cidx = lane & 15;
    f32x4 acc[4][4] = {};
    const uint4* pk = (const uint4*)(g_pk + (w >= 2 ? PK_CLF_IN : PK_ENC_IN));
#pragma unroll
    for (int k0 = 0; k0 < 2; k0++) {
        FragCast a[4], b[4];
#pragma unroll
        for (int mt = 0; mt < 4; mt++)
            a[mt].u = *(const uint4*)(&xs[mt * 16 + cidx][k0 * 32 + q * 8]);
#pragma unroll
        for (int nt = 0; nt < 4; nt++)
            b[nt].u = pk[(size_t)(k0 * 8 + (w & 1) * 4 + nt) * 64 + lane];
#pragma unroll
        for (int mt = 0; mt < 4; mt++)
#pragma unroll
            for (int nt = 0; nt < 4; nt++)
                acc[mt][nt] = __builtin_amdgcn_mfma_f32_16x16x32_bf16(
                    a[mt].f, b[nt].f, acc[mt][nt], 0, 0, 0);
    }
    const float* bp = (w >= 2) ? cb : eb;
#pragma unroll
    for (int nt = 0; nt < 4; nt++) {
        const int mcol = (w & 1) * 64 + nt * 16 + cidx;
        const float bv = bp[mcol];
#pragma unroll
        for (int mt = 0; mt < 4; mt++)
#pragma unroll
            for (int r = 0; r < 4; r++)
                ob[mt * 16 + q * 4 + r][w * 64 + nt * 16 + cidx] =
                    __float2bfloat16(fmaxf(acc[mt][nt][r] + bv, 0.f));
    }
    __syncthreads();
#pragma unroll
    for (int it = 0; it < 8; it++) {
        int idx = t + it * 256;
        int r = idx >> 5, c = idx & 31;
        uint4 v = *(const uint4*)(&ob[r][c * 8]);
        uint2 v8 = bf8pack(v);
        if (c < 16) {
            ((uint4*)(g_h  + (size_t)(node0 + r) * kD))[c] = v;
            ((uint2*)(g_h8 + (size_t)(node0 + r) * kD))[c] = v8;
        } else {
            ((uint4*)(g_hc  + (size_t)(node0 + r) * kD))[c - 16] = v;
            ((uint2*)(g_hc8 + (size_t)(node0 + r) * kD))[c - 16] = v8;
        }
    }
}

// fp8x8 (uint2) accumulate into 4 f32x2 regs
__device__ inline void f8acc(uint2 v, f32x2 wt, f32x2& c0, f32x2& c1, f32x2& c2, f32x2& c3) {
    c0 = c0 + __builtin_amdgcn_cvt_pk_f32_fp8(v.x, false) * wt;
    c1 = c1 + __builtin_amdgcn_cvt_pk_f32_fp8(v.x, true)  * wt;
    c2 = c2 + __builtin_amdgcn_cvt_pk_f32_fp8(v.y, false) * wt;
    c3 = c3 + __builtin_amdgcn_cvt_pk_f32_fp8(v.y, true)  * wt;
}
__device__ inline void f8sum(uint2 v, f32x2& c0, f32x2& c1, f32x2& c2, f32x2& c3) {
    c0 = c0 + __builtin_amdgcn_cvt_pk_f32_fp8(v.x, false);
    c1 = c1 + __builtin_amdgcn_cvt_pk_f32_fp8(v.x, true);
    c2 = c2 + __builtin_amdgcn_cvt_pk_f32_fp8(v.y, false);
    c3 = c3 + __builtin_amdgcn_cvt_pk_f32_fp8(v.y, true);
}

// CSR aggregation (R15-measured form): z[n] = h[n](bf16) + sum_j h8[col](fp8)*att?.
// 16 lanes/node (uint2 = 8 dims each), x4 unroll. No LDS -> full occupancy.
__global__ __launch_bounds__(256) void agg_csr_kernel(int src_sel, int use_att) {
    const int t = threadIdx.x;
    const int node = blockIdx.x * 16 + (t >> 4);
    const int li = t & 15;
    const uint4* __restrict__ src  = (const uint4*)bsel(src_sel);
    const uint2* __restrict__ src8 = (const uint2*)(src_sel == 0 ? g_h8 : g_hc8);
    f32x2 c0 = {0.f, 0.f}, c1 = {0.f, 0.f}, c2 = {0.f, 0.f}, c3 = {0.f, 0.f};
    if (node < kN) {
        const uint4 sv = src[(size_t)node * 16 + li];  // self term stays bf16
        c0 = (f32x2){bflo(sv.x), bfhi(sv.x)};
        c1 = (f32x2){bflo(sv.y), bfhi(sv.y)};
        c2 = (f32x2){bflo(sv.z), bfhi(sv.z)};
        c3 = (f32x2){bflo(sv.w), bfhi(sv.w)};
        const int beg = g_rowptr[node], end = g_rowptr[node + 1];
        int j = beg;
        if (use_att) {
            for (; j + 4 <= end; j += 4) {
                const uint2 v0 = src8[(size_t)g_cols[j    ] * 16 + li];
                const uint2 v1 = src8[(size_t)g_cols[j + 1] * 16 + li];
                const uint2 v2 = src8[(size_t)g_cols[j + 2] * 16 + li];
                const uint2 v3 = src8[(size_t)g_cols[j + 3] * 16 + li];
                const float w0 = g_atts[j],     w1 = g_atts[j + 1];
                const float w2 = g_atts[j + 2], w3 = g_atts[j + 3];
                f8acc(v0, (f32x2){w0, w0}, c0, c1, c2, c3);
                f8acc(v1, (f32x2){w1, w1}, c0, c1, c2, c3);
                f8acc(v2, (f32x2){w2, w2}, c0, c1, c2, c3);
                f8acc(v3, (f32x2){w3, w3}, c0, c1, c2, c3);
            }
            for (; j < end; j++) {
                const uint2 v = src8[(size_t)g_cols[j] * 16 + li];
                const float wt = g_atts[j];
                f8acc(v, (f32x2){wt, wt}, c0, c1, c2, c3);
            }
        } else {
            for (; j + 4 <= end; j += 4) {
                const uint2 v0 = src8[(size_t)g_cols[j    ] * 16 + li];
                const uint2 v1 = src8[(size_t)g_cols[j + 1] * 16 + li];
                const uint2 v2 = src8[(size_t)g_cols[j + 2] * 16 + li];
                const uint2 v3 = src8[(size_t)g_cols[j + 3] * 16 + li];
                f8sum(v0, c0, c1, c2, c3);
                f8sum(v1, c0, c1, c2, c3);
                f8sum(v2, c0, c1, c2, c3);
                f8sum(v3, c0, c1, c2, c3);
            }
            for (; j < end; j++) {
                const uint2 v = src8[(size_t)g_cols[j] * 16 + li];
                f8sum(v, c0, c1, c2, c3);
            }
        }
    }
    union { uint4 u; __hip_bfloat16 h[8]; } o;
    o.h[0] = __float2bfloat16(c0.x); o.h[1] = __float2bfloat16(c0.y);
    o.h[2] = __float2bfloat16(c1.x); o.h[3] = __float2bfloat16(c1.y);
    o.h[4] = __float2bfloat16(c2.x); o.h[5] = __float2bfloat16(c2.y);
    o.h[6] = __float2bfloat16(c3.x); o.h[7] = __float2bfloat16(c3.y);
    ((uint4*)g_z)[(size_t)node * 16 + li] = o.u;
}

// MFMA GIN MLP: h_dst = [relu]( relu(z @ W1 + b1) @ W2 + b2 ) + fp8 mirror.
__global__ __launch_bounds__(256) void gin_mlp_mfma(
    int dst_sel, size_t pkW1off, size_t pkW2off,
    const float* __restrict__ b1, const float* __restrict__ b2, int relu_out) {
    __shared__ __hip_bfloat16 zs[64][136];
    __shared__ __hip_bfloat16 hid[64][264];
    const int t = threadIdx.x, lane = t & 63, w = t >> 6;
    const int node0 = blockIdx.x * 64;
    __hip_bfloat16* hp = bsel(dst_sel);
    unsigned char* mp = dst_sel == 0 ? g_h8 : g_hc8;

    {
        const uint4* src = (const uint4*)(g_z + (size_t)node0 * kD);
#pragma unroll
        for (int it = 0; it < 4; it++) {
            int idx = t + it * 256;
            int r = idx >> 4, c = idx & 15;
            *(uint4*)(&zs[r][c * 8]) = src[(size_t)r * 16 + c];
        }
    }
    __syncthreads();

    const int q = lane >> 4, cidx = lane & 15;

    f32x4 acc1[4][4] = {};
    const uint4* pk1 = (const uint4*)(g_pk + pkW1off);
    for (int k0 = 0; k0 < 4; k0++) {
        FragCast a[4], b[4];
#pragma unroll
        for (int mt = 0; mt < 4; mt++)
            a[mt].u = *(const uint4*)(&zs[mt * 16 + cidx][k0 * 32 + q * 8]);
#pragma unroll
        for (int nt = 0; nt < 4; nt++)
            b[nt].u = pk1[(size_t)(k0 * 16 + (w * 4 + nt)) * 64 + lane];
#pragma unroll
        for (int mt = 0; mt < 4; mt++)
#pragma unroll
            for (int nt = 0; nt < 4; nt++)
                acc1[mt][nt] = __builtin_amdgcn_mfma_f32_16x16x32_bf16(
                    a[mt].f, b[nt].f, acc1[mt][nt], 0, 0, 0);
    }
#pragma unroll
    for (int nt = 0; nt < 4; nt++) {
        const int col = w * 64 + nt * 16 + cidx;
        const float bv = b1[col];
#pragma unroll
        for (int mt = 0; mt < 4; mt++)
#pragma unroll
            for (int r = 0; r < 4; r++)
                hid[mt * 16 + q * 4 + r][col] =
                    __float2bfloat16(fmaxf(acc1[mt][nt][r] + bv, 0.f));
    }
    __syncthreads();

    f32x4 acc2[4][2] = {};
    const uint4* pk2 = (const uint4*)(g_pk + pkW2off);
    for (int k0 = 0; k0 < 8; k0++) {
        FragCast a[4], b[2];
#pragma unroll
        for (int mt = 0; mt < 4; mt++)
            a[mt].u = *(const uint4*)(&hid[mt * 16 + cidx][k0 * 32 + q * 8]);
#pragma unroll
        for (int nt = 0; nt < 2; nt++)
            b[nt].u = pk2[(size_t)(k0 * 8 + (w * 2 + nt)) * 64 + lane];
#pragma unroll
        for (int mt = 0; mt < 4; mt++)
#pragma unroll
            for (int nt = 0; nt < 2; nt++)
                acc2[mt][nt] = __builtin_amdgcn_mfma_f32_16x16x32_bf16(
                    a[mt].f, b[nt].f, acc2[mt][nt], 0, 0, 0);
    }
#pragma unroll
    for (int nt = 0; nt < 2; nt++) {
        const int col = w * 32 + nt * 16 + cidx;
        const float bv = b2[col];
#pragma unroll
        for (int mt = 0; mt < 4; mt++)
#pragma unroll
            for (int r = 0; r < 4; r++) {
                float v = acc2[mt][nt][r] + bv;
                if (relu_out) v = fmaxf(v, 0.f);
                zs[mt * 16 + q * 4 + r][col] = __float2bfloat16(v);
            }
    }
    __syncthreads();
    {
        uint4* dst = (uint4*)(hp + (size_t)node0 * kD);
        uint2* md  = (uint2*)(mp + (size_t)node0 * kD);
#pragma unroll
        for (int it = 0; it < 4; it++) {
            int idx = t + it * 256;
            int r = idx >> 4, c = idx & 15;
            uint4 v = *(const uint4*)(&zs[r][c * 8]);
            dst[(size_t)r * 16 + c] = v;
            md[(size_t)r * 16 + c] = bf8pack(v);
        }
    }
}

// A (bf16) / B (fp8 e4m3, HW packed cvt) = enc_h @ attW1_{top,bot} (+b1 for A).
__global__ __launch_bounds__(256) void att_dense_mfma(const float* __restrict__ b1) {
    __shared__ __hip_bfloat16 zs[64][136];
    __shared__ __hip_bfloat16 ob[64][264];
    const int t = threadIdx.x, lane = t & 63, w = t >> 6;
    const int node0 = blockIdx.x * 64;
    const int mat = blockIdx.y >> 1, half = blockIdx.y & 1;
    const size_t pkoff = mat ? PK_ATT_BOT : PK_ATT_TOP;

    const uint4* src = (const uint4*)(g_h + (size_t)node0 * kD);
#pragma unroll
    for (int it = 0; it < 4; it++) {
        int idx = t + it * 256;
        int r = idx >> 4, c = idx & 15;
        *(uint4*)(&zs[r][c * 8]) = src[(size_t)r * 16 + c];
    }
    __syncthreads();

    const int q = lane >> 4, cidx = lane & 15;
    f32x4 acc[4][4] = {};
    const uint4* pk = (const uint4*)(g_pk + pkoff);
    for (int k0 = 0; k0 < 4; k0++) {
        FragCast a[4], b[4];
#pragma unroll
        for (int mt = 0; mt < 4; mt++)
            a[mt].u = *(const uint4*)(&zs[mt * 16 + cidx][k0 * 32 + q * 8]);
#pragma unroll
        for (int nt = 0; nt < 4; nt++)
            b[nt].u = pk[(size_t)(k0 * 32 + (half * 16 + w * 4 + nt)) * 64 + lane];
#pragma unroll
        for (int mt = 0; mt < 4; mt++)
#pragma unroll
            for (int nt = 0; nt < 4; nt++)
                acc[mt][nt] = __builtin_amdgcn_mfma_f32_16x16x32_bf16(
                    a[mt].f, b[nt].f, acc[mt][nt], 0, 0, 0);
    }
#pragma unroll
    for (int nt = 0; nt < 4; nt++) {
        const int lcol = w * 64 + nt * 16 + cidx;
        const float bv = (mat == 0) ? b1[half * 256 + lcol] : 0.f;
#pragma unroll
        for (int mt = 0; mt < 4; mt++)
#pragma unroll
            for (int r = 0; r < 4; r++)
                ob[mt * 16 + q * 4 + r][lcol] = __float2bfloat16(acc[mt][nt][r] + bv);
    }
    __syncthreads();
    if (mat == 0) {   // A: bf16
        uint4* dst = (uint4*)(g_A + (size_t)node0 * kA4 + half * 256);
#pragma unroll
        for (int it = 0; it < 8; it++) {
            int idx = t + it * 256;
            int r = idx >> 5, c = idx & 31;
            dst[(size_t)r * 64 + c] = *(const uint4*)(&ob[r][c * 8]);
        }
    } else {          // B: fp8 e4m3
        uint2* dst = (uint2*)(g_Bf8 + (size_t)node0 * kA4 + half * 256);
#pragma unroll
        for (int it = 0; it < 8; it++) {
            int idx = t + it * 256;
            int r = idx >> 5, c = idx & 31;
            dst[(size_t)r * 64 + c] = bf8pack(*(const uint4*)(&ob[r][c * 8]));
        }
    }
}

// Packed-f32 fp8 dot: 16 dims as 8 f32x2 lanes; HW v_cvt_pk_f32_fp8 decode.
__device__ inline float edge_dot16_f8(const f32x2* a2, const f32x2* w2, uint4 bu) {
    const f32x2 zero = {0.f, 0.f};
    f32x2 p = zero;
    const unsigned wd[4] = {bu.x, bu.y, bu.z, bu.w};
#pragma unroll
    for (int k = 0; k < 4; k++) {
        f32x2 b0 = __builtin_amdgcn_cvt_pk_f32_fp8(wd[k], false);
        f32x2 b1 = __builtin_amdgcn_cvt_pk_f32_fp8(wd[k], true);
        f32x2 t0 = __builtin_elementwise_max(a2[2 * k] + b0, zero);
        f32x2 t1 = __builtin_elementwise_max(a2[2 * k + 1] + b1, zero);
        p = p + t0 * w2[2 * k];
        p = p + t1 * w2[2 * k + 1];
    }
    return p.x + p.y;
}

// att in CSR order (R16-measured best form): 32 lanes/edge, 2 edges/wave,
// x2 unroll (4 edges/iter), VGPR-44.
__global__ __launch_bounds__(256) void att_edge_csr(
    const float* __restrict__ W2, const float* __restrict__ b2) {
    const int node = blockIdx.x * 4 + (threadIdx.x >> 6);  // wave per node
    const int lane = threadIdx.x & 63;
    const int sub = lane >> 5;   // edge sub-group 0/1
    const int li  = lane & 31;
    const int m0 = li * 16;      // dims [m0, m0+16)
    const uint4 au0 = *(const uint4*)(g_A + (size_t)node * kA4 + m0);
    const uint4 au1 = *(const uint4*)(g_A + (size_t)node * kA4 + m0 + 8);
    f32x2 a2[8];
    a2[0] = (f32x2){bflo(au0.x), bfhi(au0.x)};
    a2[1] = (f32x2){bflo(au0.y), bfhi(au0.y)};
    a2[2] = (f32x2){bflo(au0.z), bfhi(au0.z)};
    a2[3] = (f32x2){bflo(au0.w), bfhi(au0.w)};
    a2[4] = (f32x2){bflo(au1.x), bfhi(au1.x)};
    a2[5] = (f32x2){bflo(au1.y), bfhi(au1.y)};
    a2[6] = (f32x2){bflo(au1.z), bfhi(au1.z)};
    a2[7] = (f32x2){bflo(au1.w), bfhi(au1.w)};
    f32x2 w2[8];
#pragma unroll
    for (int k = 0; k < 8; k++) {
        const float2 wk = *(const float2*)(W2 + m0 + 2 * k);
        w2[k] = (f32x2){wk.x, wk.y};
    }
    const float bb = b2[0];
    const int beg = g_rowptr[node], end = g_rowptr[node + 1];

    int j = beg;
    for (; j + 4 <= end; j += 4) {
        const int c0 = g_cols[j + sub];
        const int c1 = g_cols[j + 2 + sub];
        const uint4 b0 = *(const uint4*)(g_Bf8 + (size_t)c0 * kA4 + m0);
        const uint4 b1 = *(const uint4*)(g_Bf8 + (size_t)c1 * kA4 + m0);
        float s0 = edge_dot16_f8(a2, w2, b0);
        float s1 = edge_dot16_f8(a2, w2, b1);
        for (int off = 16; off > 0; off >>= 1) {
            s0 += __shfl_down(s0, off);
            s1 += __shfl_down(s1, off);
        }
        if (li == 0) {
            g_atts[j + sub]     = 1.f / (1.f + __expf(-(s0 + bb)));
            g_atts[j + 2 + sub] = 1.f / (1.f + __expf(-(s1 + bb)));
        }
    }
    for (; j < end; j += 2) {
        const int je = j + sub;
        const int jc = (je < end) ? je : (end - 1);
        const int c = g_cols[jc];
        const uint4 b0 = *(const uint4*)(g_Bf8 + (size_t)c * kA4 + m0);
        float s = edge_dot16_f8(a2, w2, b0);
        for (int off = 16; off > 0; off >>= 1) s += __shfl_down(s, off);
        if (li == 0 && je < end)
            g_atts[je] = 1.f / (1.f + __expf(-(s + bb)));
    }
}

// Segmented mean-pool over sorted batch; final classifier h lives in g_hc.
__global__ __launch_bounds__(64) void pool_kernel(const int* __restrict__ batch) {
    const int t = threadIdx.x;
    int n = blockIdx.x * PCHUNK;
    const int nend = n + PCHUNK;
    const unsigned* __restrict__ hc = (const unsigned*)g_hc;
    int gcur = batch[n];
    float a0 = 0.f, a1 = 0.f, cv = 0.f;
    for (; n < nend; n++) {
        const int g = batch[n];
        if (g != gcur) {
            atomicAdd(&g_pool[gcur * kD + 2 * t], a0);
            atomicAdd(&g_pool[gcur * kD + 2 * t + 1], a1);
            if (t == 0) atomicAdd(&g_gcnt[gcur], cv);
            a0 = a1 = cv = 0.f; gcur = g;
        }
        unsigned v = hc[(size_t)n * 64 + t];
        a0 += bflo(v); a1 += bfhi(v);
        cv += 1.f;
    }
    atomicAdd(&g_pool[gcur * kD + 2 * t], a0);
    atomicAdd(&g_pool[gcur * kD + 2 * t + 1], a1);
    if (t == 0) atomicAdd(&g_gcnt[gcur], cv);
}

__global__ __launch_bounds__(640) void head_kernel(
    const float* __restrict__ hW, const float* __restrict__ hb,
    float* __restrict__ out) {
    const int t = threadIdx.x;
    const int g = t / kOUT, o = t - g * kOUT;
    const float c = fmaxf(g_gcnt[g], 1.f);
    const float inv = 1.f / c;
    float acc = hb[o];
    for (int k = 0; k < kD; k++)
        acc = fmaf(g_pool[g * kD + k] * inv, hW[k * kOUT + o], acc);
    out[(size_t)g * kOUT + o] = acc;
}

extern "C" void kernel_launch(void* const* d_in, const int* in_sizes, int n_in,
                              void* d_out, int out_size, void* d_ws, size_t ws_size,
                              hipStream_t stream) {
    const float* x        = (const float*)d_in[0];
    const int*   ei       = (const int*)d_in[1];
    const int*   row      = ei;
    const int*   col      = ei + kE;
    const int*   batch    = (const int*)d_in[2];
    const float* enc_in_W = (const float*)d_in[4];
    const float* enc_in_b = (const float*)d_in[5];
    const float* enc_W1   = (const float*)d_in[6];
    const float* enc_b1   = (const float*)d_in[7];
    const float* enc_W2   = (const float*)d_in[8];
    const float* enc_b2   = (const float*)d_in[9];
    const float* att_W1   = (const float*)d_in[10];
    const float* att_b1   = (const float*)d_in[11];
    const float* att_W2   = (const float*)d_in[12];
    const float* att_b2   = (const float*)d_in[13];
    const float* clf_in_W = (const float*)d_in[14];
    const float* clf_in_b = (const float*)d_in[15];
    const float* clf_W1   = (const float*)d_in[16];
    const float* clf_b1   = (const float*)d_in[17];
    const float* clf_W2   = (const float*)d_in[18];
    const float* clf_b2   = (const float*)d_in[19];
    const float* head_W   = (const float*)d_in[20];
    const float* head_b   = (const float*)d_in[21];
    float* out = (float*)d_out;

    const dim3 blk(256);
    const int eblocks = (kE + 255) / 256;

    // ---- weight prepack ----
    SrcPtrs sp;
    for (int l = 0; l < 3; l++) {
        sp.p[0 + l] = enc_W1 + (size_t)l * kD * kH;
        sp.p[3 + l] = enc_W2 + (size_t)l * kH * kD;
        sp.p[6 + l] = clf_W1 + (size_t)l * kD * kH;
        sp.p[9 + l] = clf_W2 + (size_t)l * kH * kD;
    }
    sp.p[12] = att_W1;
    sp.p[13] = att_W1 + (size_t)kD * kA4;
    sp.p[14] = enc_in_W;
    sp.p[15] = clf_in_W;
    prepack_kernel<<<1056, dim3(64), 0, stream>>>(sp);

    // ---- CSR build (hierarchical scan) ----
    zero_prep_kernel<<<(kN + 255) / 256, blk, 0, stream>>>();
    hist_kernel<<<eblocks, blk, 0, stream>>>(row);
    scan1_kernel<<<SBLK, blk, 0, stream>>>();
    scan2_kernel<<<1, blk, 0, stream>>>();
    scan3_kernel<<<SBLK, blk, 0, stream>>>();
    scatter_kernel<<<eblocks, blk, 0, stream>>>(row, col);

    input_proj_mfma<<<kNP / 64, blk, 0, stream>>>(x, enc_in_b, clf_in_b);

    // ---- encoder GIN stack (agg: g_h -> g_z; mlp: g_z -> g_h) ----
    for (int l = 0; l < 3; l++) {
        agg_csr_kernel<<<kNP / 16, blk, 0, stream>>>(0, 0);
        gin_mlp_mfma<<<kNP / 64, blk, 0, stream>>>(
            0, PK_ENC_W1(l), PK_ENC_W2(l),
            enc_b1 + (size_t)l * kH, enc_b2 + (size_t)l * kD, (l < 2) ? 1 : 0);
    }

    // ---- edge attention (A bf16 / B fp8 from g_h; att written in CSR order) ----
    att_dense_mfma<<<dim3(kNP / 64, 4), blk, 0, stream>>>(att_b1);
    att_edge_csr<<<kN / 4, blk, 0, stream>>>(att_W2, att_b2);

    // ---- classifier GIN stack (agg: g_hc -> g_z; mlp: g_z -> g_hc) ----
    for (int l = 0; l < 3; l++) {
        agg_csr_kernel<<<kNP / 16, blk, 0, stream>>>(1, 1);
        gin_mlp_mfma<<<kNP / 64, blk, 0, stream>>>(
            1, PK_CLF_W1(l), PK_CLF_W2(l),
            clf_b1 + (size_t)l * kH, clf_b2 + (size_t)l * kD, (l < 2) ? 1 : 0);
    }

    // ---- mean pool + head ----
    pool_kernel<<<kN / PCHUNK, dim3(64), 0, stream>>>(batch);
    head_kernel<<<1, dim3(kG * kOUT), 0, stream>>>(head_W, head_b, out);
}